// Round 5
// baseline (888.220 us; speedup 1.0000x reference)
//
#include <hip/hip_runtime.h>
#include <hip/hip_bf16.h>
#include <math.h>

#define V 32000
#define T 128
#define B 64
#define E 32
#define H 8
#define TB (T*B)   // 8192

#define NT 320     // 5 waves; 4 cols/thread -> 1280 cols per chunk
#define NW 5
#define NCH 25     // 32000 / 1280 v-chunks
#define G2 64      // row-groups pass 2 (128 rows/block)

// ---------------- params struct ----------------
struct P1 {
  const int* x; const float* emb;
  const float* Wf1; const float* bf1; const float* Wi1; const float* bi1;
  const float* WC1; const float* bC1; const float* Wo1; const float* bo1;
  const float* Wf2; const float* bf2; const float* Wi2; const float* bi2;
  const float* WC2; const float* bC2; const float* Wo2; const float* bo2;
};

__device__ __forceinline__ float sigm_f(float x) { return 1.f / (1.f + __expf(-x)); }
__device__ __forceinline__ float tanh_f(float x) { float e = __expf(2.f * x); return 1.f - 2.f / (e + 1.f); }

// ---------------- kernel 1: embed + e-part projections (bias folded in) ----------------
__global__ __launch_bounds__(256) void k_embed(P1 p, float* __restrict__ pe) {
  int r = blockIdx.x * 256 + threadIdx.x;
  int idx = p.x[r];
  const float* e = p.emb + (long)idx * E;
  float ev[E];
  #pragma unroll
  for (int k = 0; k < E; k += 4) {
    float4 v4 = *(const float4*)(e + k);
    ev[k] = v4.x; ev[k+1] = v4.y; ev[k+2] = v4.z; ev[k+3] = v4.w;
  }
  #pragma unroll
  for (int d = 0; d < 2; ++d) {
    const float* Wf = d ? p.Wf2 : p.Wf1;
    const float* Wi = d ? p.Wi2 : p.Wi1;
    const float* Wo = d ? p.Wo2 : p.Wo1;
    const float* WC = d ? p.WC2 : p.WC1;
    const float* bC = d ? p.bC2 : p.bC1;
    float af = (d ? p.bf2 : p.bf1)[0];
    float ai = (d ? p.bi2 : p.bi1)[0];
    float ao = (d ? p.bo2 : p.bo1)[0];
    float ac[H];
    #pragma unroll
    for (int j = 0; j < H; ++j) ac[j] = bC[j];
    #pragma unroll
    for (int k = 0; k < E; ++k) {
      float ek = ev[k];
      af += ek * Wf[8 + k];
      ai += ek * Wi[8 + k];
      ao += ek * Wo[8 + k];
      #pragma unroll
      for (int j = 0; j < H; ++j) ac[j] += ek * WC[(8 + k) * H + j];
    }
    float* ped = pe + d * 11 * TB;
    ped[0 * TB + r] = af;
    ped[1 * TB + r] = ai;
    ped[2 * TB + r] = ao;
    #pragma unroll
    for (int j = 0; j < H; ++j) ped[(3 + j) * TB + r] = ac[j];
  }
}

// ---------------- kernel 2: sequential LSTM (one block per direction) ----------------
__global__ __launch_bounds__(64) void k_lstm(P1 p, const float* __restrict__ pe, float* __restrict__ hcat) {
  int dir = blockIdx.x;
  int lane = threadIdx.x;
  const float* Wf = dir ? p.Wf2 : p.Wf1;
  const float* Wi = dir ? p.Wi2 : p.Wi1;
  const float* Wo = dir ? p.Wo2 : p.Wo1;
  const float* WC = dir ? p.WC2 : p.WC1;
  float wf[8], wi[8], wo[8], wc[8][8];
  #pragma unroll
  for (int k = 0; k < 8; ++k) { wf[k] = Wf[k]; wi[k] = Wi[k]; wo[k] = Wo[k]; }
  #pragma unroll
  for (int k = 0; k < 8; ++k)
    #pragma unroll
    for (int j = 0; j < 8; ++j) wc[k][j] = WC[k * H + j];

  float h[8], C[8];
  #pragma unroll
  for (int j = 0; j < 8; ++j) { h[j] = 0.f; C[j] = 0.f; }

  const float* ped = pe + dir * 11 * TB;

  int tf = dir ? (T - 1) : 0;
  int rf = tf * B + lane;
  float nf = ped[0 * TB + rf], ni = ped[1 * TB + rf], no_ = ped[2 * TB + rf];
  float nc[8];
  #pragma unroll
  for (int j = 0; j < 8; ++j) nc[j] = ped[(3 + j) * TB + rf];

  for (int s = 0; s < T; ++s) {
    int t = dir ? (T - 1 - s) : s;
    int r = t * B + lane;
    float af = nf, ai = ni, ao = no_;
    float ac[8];
    #pragma unroll
    for (int j = 0; j < 8; ++j) ac[j] = nc[j];

    if (s + 1 < T) {
      int t2 = dir ? (T - 2 - s) : (s + 1);
      int r2 = t2 * B + lane;
      nf = ped[0 * TB + r2]; ni = ped[1 * TB + r2]; no_ = ped[2 * TB + r2];
      #pragma unroll
      for (int j = 0; j < 8; ++j) nc[j] = ped[(3 + j) * TB + r2];
    }

    float* hc = hcat + r * 16 + dir * 8;
    #pragma unroll
    for (int j = 0; j < 8; ++j) hc[j] = h[j];

    #pragma unroll
    for (int k = 0; k < 8; ++k) {
      float hk = h[k];
      af += hk * wf[k];
      ai += hk * wi[k];
      ao += hk * wo[k];
      #pragma unroll
      for (int j = 0; j < 8; ++j) ac[j] += hk * wc[k][j];
    }
    float f = sigm_f(af), i = sigm_f(ai), o = sigm_f(ao);
    #pragma unroll
    for (int j = 0; j < 8; ++j) {
      float Cn = f * C[j] + i + tanh_f(ac[j]);
      C[j] = Cn;
      h[j] = o * tanh_f(Cn);
    }
  }
}

// ---------------- pass 1: full-row sum-exp -> Z, one block = 16 rows x all V ----------------
// sum[16] accumulates in registers across all 25 chunks; one reduce per row at the end.
__global__ __launch_bounds__(NT) void k_sum(const float* __restrict__ hcat,
                                            const float* __restrict__ Wout,
                                            const float* __restrict__ bout,
                                            float* __restrict__ Z) {
  __shared__ float sTH[16 * 16];
  __shared__ float sP[16][NW];
  int tid = threadIdx.x;
  int wave = tid >> 6, lane = tid & 63;
  int r0 = blockIdx.x * 16;

  if (tid < 256) sTH[tid] = hcat[r0 * 16 + tid];
  __syncthreads();

  float sum[16];
  #pragma unroll
  for (int q = 0; q < 16; ++q) sum[q] = 0.f;

  for (int c = 0; c < NCH; ++c) {
    int col4 = c * (NT * 4) + tid * 4;
    float4 w[16];
    #pragma unroll
    for (int k = 0; k < 16; ++k) w[k] = *(const float4*)(Wout + k * V + col4);
    float4 bb = *(const float4*)(bout + col4);
    #pragma unroll
    for (int q = 0; q < 16; ++q) {
      const float4* th4 = (const float4*)(sTH + q * 16);
      float4 t0 = th4[0], t1 = th4[1], t2 = th4[2], t3 = th4[3];
      float th[16] = {t0.x,t0.y,t0.z,t0.w, t1.x,t1.y,t1.z,t1.w,
                      t2.x,t2.y,t2.z,t2.w, t3.x,t3.y,t3.z,t3.w};
      float lx = bb.x, ly = bb.y, lz = bb.z, lw = bb.w;
      #pragma unroll
      for (int k = 0; k < 16; ++k) {
        lx += th[k] * w[k].x; ly += th[k] * w[k].y;
        lz += th[k] * w[k].z; lw += th[k] * w[k].w;
      }
      sum[q] += __expf(lx) + __expf(ly) + __expf(lz) + __expf(lw);
    }
  }

  #pragma unroll
  for (int q = 0; q < 16; ++q) {
    float s = sum[q];
    #pragma unroll
    for (int off = 32; off >= 1; off >>= 1) s += __shfl_xor(s, off);
    if (lane == 0) sP[q][wave] = s;
  }
  __syncthreads();
  if (tid < 16) {
    float s = sP[tid][0] + sP[tid][1] + sP[tid][2] + sP[tid][3] + sP[tid][4];
    Z[r0 + tid] = logf(s);
  }
}

// ---------------- pass 2: recompute logits, subtract Z, write ----------------
// grid (NCH, G2); whole 128x16 hcat tile + Z staged once, then sync-free streaming.
__global__ __launch_bounds__(NT) void k_wr(const float* __restrict__ hcat,
                                           const float* __restrict__ Wout,
                                           const float* __restrict__ bout,
                                           const float* __restrict__ Z,
                                           float* __restrict__ out) {
  const int RPB = TB / G2;                 // 128
  __shared__ float sTH[RPB * 16];          // 8 KB
  __shared__ float sZ[RPB];
  int tid = threadIdx.x;
  int chunk = blockIdx.x;
  int row0 = blockIdx.y * RPB;
  int col4 = chunk * (NT * 4) + tid * 4;

  float4 w[16];
  #pragma unroll
  for (int k = 0; k < 16; ++k) w[k] = *(const float4*)(Wout + k * V + col4);
  float4 bb = *(const float4*)(bout + col4);

  for (int i = tid; i < RPB * 16; i += NT) sTH[i] = hcat[row0 * 16 + i];
  for (int i = tid; i < RPB; i += NT) sZ[i] = Z[row0 + i];
  __syncthreads();

  for (int rt = 0; rt < RPB / 16; ++rt) {
    #pragma unroll
    for (int q = 0; q < 16; ++q) {
      int rq = rt * 16 + q;
      const float4* th4 = (const float4*)(sTH + rq * 16);
      float4 t0 = th4[0], t1 = th4[1], t2 = th4[2], t3 = th4[3];
      float th[16] = {t0.x,t0.y,t0.z,t0.w, t1.x,t1.y,t1.z,t1.w,
                      t2.x,t2.y,t2.z,t2.w, t3.x,t3.y,t3.z,t3.w};
      float lx = bb.x, ly = bb.y, lz = bb.z, lw = bb.w;
      #pragma unroll
      for (int k = 0; k < 16; ++k) {
        lx += th[k] * w[k].x; ly += th[k] * w[k].y;
        lz += th[k] * w[k].z; lw += th[k] * w[k].w;
      }
      float Zq = sZ[rq];
      float4 o4;
      o4.x = lx - Zq; o4.y = ly - Zq; o4.z = lz - Zq; o4.w = lw - Zq;
      *(float4*)(out + (long)(row0 + rq) * V + col4) = o4;
    }
  }
}

extern "C" void kernel_launch(void* const* d_in, const int* in_sizes, int n_in,
                              void* d_out, int out_size, void* d_ws, size_t ws_size,
                              hipStream_t stream) {
  (void)in_sizes; (void)n_in; (void)out_size; (void)ws_size;
  P1 p;
  p.x   = (const int*)  d_in[0];
  p.emb = (const float*)d_in[1];
  p.Wf1 = (const float*)d_in[2];  p.bf1 = (const float*)d_in[3];
  p.Wi1 = (const float*)d_in[4];  p.bi1 = (const float*)d_in[5];
  p.WC1 = (const float*)d_in[6];  p.bC1 = (const float*)d_in[7];
  p.Wo1 = (const float*)d_in[8];  p.bo1 = (const float*)d_in[9];
  p.Wf2 = (const float*)d_in[10]; p.bf2 = (const float*)d_in[11];
  p.Wi2 = (const float*)d_in[12]; p.bi2 = (const float*)d_in[13];
  p.WC2 = (const float*)d_in[14]; p.bC2 = (const float*)d_in[15];
  p.Wo2 = (const float*)d_in[16]; p.bo2 = (const float*)d_in[17];
  const float* Wout = (const float*)d_in[18];
  const float* bout = (const float*)d_in[19];

  float* pe   = (float*)d_ws;            // 2*11*TB = 180224 f
  float* hcat = pe + 2 * 11 * TB;        // TB*16   = 131072 f
  float* Zr   = hcat + TB * 16;          // TB      =   8192 f
  float* out  = (float*)d_out;

  k_embed <<<dim3(TB / 256),  dim3(256), 0, stream>>>(p, pe);
  k_lstm  <<<dim3(2),         dim3(64),  0, stream>>>(p, pe, hcat);
  k_sum   <<<dim3(TB / 16),   dim3(NT),  0, stream>>>(hcat, Wout, bout, Zr);
  k_wr    <<<dim3(NCH, G2),   dim3(NT),  0, stream>>>(hcat, Wout, bout, Zr, out);
}

// Round 6
// 768.804 us; speedup vs baseline: 1.1553x; 1.1553x over previous
//
#include <hip/hip_runtime.h>
#include <hip/hip_bf16.h>
#include <math.h>

#define V 32000
#define T 128
#define B 64
#define E 32
#define H 8
#define TB (T*B)   // 8192

#define NT 320     // 5 waves; 4 cols/thread -> 1280 cols per chunk
#define NW 5
#define NCH 25     // 32000 / 1280 v-chunks
#define G1 32      // row-groups pass 1 (256 rows/block)
#define G2 64      // row-groups pass 2 (128 rows/block)

// ---------------- params struct ----------------
struct P1 {
  const int* x; const float* emb;
  const float* Wf1; const float* bf1; const float* Wi1; const float* bi1;
  const float* WC1; const float* bC1; const float* Wo1; const float* bo1;
  const float* Wf2; const float* bf2; const float* Wi2; const float* bi2;
  const float* WC2; const float* bC2; const float* Wo2; const float* bo2;
};

__device__ __forceinline__ float sigm_f(float x) { return 1.f / (1.f + __expf(-x)); }
__device__ __forceinline__ float tanh_f(float x) { float e = __expf(2.f * x); return 1.f - 2.f / (e + 1.f); }

// ---------------- kernel 1: embed + e-part projections (bias folded in) ----------------
__global__ __launch_bounds__(256) void k_embed(P1 p, float* __restrict__ pe) {
  int r = blockIdx.x * 256 + threadIdx.x;
  int idx = p.x[r];
  const float* e = p.emb + (long)idx * E;
  float ev[E];
  #pragma unroll
  for (int k = 0; k < E; k += 4) {
    float4 v4 = *(const float4*)(e + k);
    ev[k] = v4.x; ev[k+1] = v4.y; ev[k+2] = v4.z; ev[k+3] = v4.w;
  }
  #pragma unroll
  for (int d = 0; d < 2; ++d) {
    const float* Wf = d ? p.Wf2 : p.Wf1;
    const float* Wi = d ? p.Wi2 : p.Wi1;
    const float* Wo = d ? p.Wo2 : p.Wo1;
    const float* WC = d ? p.WC2 : p.WC1;
    const float* bC = d ? p.bC2 : p.bC1;
    float af = (d ? p.bf2 : p.bf1)[0];
    float ai = (d ? p.bi2 : p.bi1)[0];
    float ao = (d ? p.bo2 : p.bo1)[0];
    float ac[H];
    #pragma unroll
    for (int j = 0; j < H; ++j) ac[j] = bC[j];
    #pragma unroll
    for (int k = 0; k < E; ++k) {
      float ek = ev[k];
      af += ek * Wf[8 + k];
      ai += ek * Wi[8 + k];
      ao += ek * Wo[8 + k];
      #pragma unroll
      for (int j = 0; j < H; ++j) ac[j] += ek * WC[(8 + k) * H + j];
    }
    float* ped = pe + d * 11 * TB;
    ped[0 * TB + r] = af;
    ped[1 * TB + r] = ai;
    ped[2 * TB + r] = ao;
    #pragma unroll
    for (int j = 0; j < H; ++j) ped[(3 + j) * TB + r] = ac[j];
  }
}

// ---------------- kernel 2: sequential LSTM (one block per direction) ----------------
__global__ __launch_bounds__(64) void k_lstm(P1 p, const float* __restrict__ pe, float* __restrict__ hcat) {
  int dir = blockIdx.x;
  int lane = threadIdx.x;
  const float* Wf = dir ? p.Wf2 : p.Wf1;
  const float* Wi = dir ? p.Wi2 : p.Wi1;
  const float* Wo = dir ? p.Wo2 : p.Wo1;
  const float* WC = dir ? p.WC2 : p.WC1;
  float wf[8], wi[8], wo[8], wc[8][8];
  #pragma unroll
  for (int k = 0; k < 8; ++k) { wf[k] = Wf[k]; wi[k] = Wi[k]; wo[k] = Wo[k]; }
  #pragma unroll
  for (int k = 0; k < 8; ++k)
    #pragma unroll
    for (int j = 0; j < 8; ++j) wc[k][j] = WC[k * H + j];

  float h[8], C[8];
  #pragma unroll
  for (int j = 0; j < 8; ++j) { h[j] = 0.f; C[j] = 0.f; }

  const float* ped = pe + dir * 11 * TB;

  int tf = dir ? (T - 1) : 0;
  int rf = tf * B + lane;
  float nf = ped[0 * TB + rf], ni = ped[1 * TB + rf], no_ = ped[2 * TB + rf];
  float nc[8];
  #pragma unroll
  for (int j = 0; j < 8; ++j) nc[j] = ped[(3 + j) * TB + rf];

  for (int s = 0; s < T; ++s) {
    int t = dir ? (T - 1 - s) : s;
    int r = t * B + lane;
    float af = nf, ai = ni, ao = no_;
    float ac[8];
    #pragma unroll
    for (int j = 0; j < 8; ++j) ac[j] = nc[j];

    if (s + 1 < T) {
      int t2 = dir ? (T - 2 - s) : (s + 1);
      int r2 = t2 * B + lane;
      nf = ped[0 * TB + r2]; ni = ped[1 * TB + r2]; no_ = ped[2 * TB + r2];
      #pragma unroll
      for (int j = 0; j < 8; ++j) nc[j] = ped[(3 + j) * TB + r2];
    }

    float* hc = hcat + r * 16 + dir * 8;
    #pragma unroll
    for (int j = 0; j < 8; ++j) hc[j] = h[j];

    #pragma unroll
    for (int k = 0; k < 8; ++k) {
      float hk = h[k];
      af += hk * wf[k];
      ai += hk * wi[k];
      ao += hk * wo[k];
      #pragma unroll
      for (int j = 0; j < 8; ++j) ac[j] += hk * wc[k][j];
    }
    float f = sigm_f(af), i = sigm_f(ai), o = sigm_f(ao);
    #pragma unroll
    for (int j = 0; j < 8; ++j) {
      float Cn = f * C[j] + i + tanh_f(ac[j]);
      C[j] = Cn;
      h[j] = o * tanh_f(Cn);
    }
  }
}

// ---------------- pass 1: partial sum-exp; Wout slice in registers, barrier-free ----
// grid (NCH, G1); block = cols [chunk*1280,+1280) x rows [rg*256,+256)
// stage all 256 rows of hcat once; per-row wave partials -> sPW (no sync); one
// final barrier; threads 0..255 write pms[row*NCH+chunk].
__global__ __launch_bounds__(NT) void k_part(const float* __restrict__ hcat,
                                             const float* __restrict__ Wout,
                                             const float* __restrict__ bout,
                                             float* __restrict__ pms) {
  const int RPB = TB / G1;                 // 256 rows
  __shared__ float sTH[RPB * 16];          // 16 KB
  __shared__ float sPW[RPB][NW];           // 5 KB
  int tid = threadIdx.x;
  int wave = tid >> 6, lane = tid & 63;
  int chunk = blockIdx.x;
  int row0 = blockIdx.y * RPB;
  int col4 = chunk * (NT * 4) + tid * 4;

  for (int i = tid; i < RPB * 16; i += NT) sTH[i] = hcat[row0 * 16 + i];
  __syncthreads();

  float4 w[16];
  #pragma unroll
  for (int k = 0; k < 16; ++k) w[k] = *(const float4*)(Wout + k * V + col4);
  float4 bb = *(const float4*)(bout + col4);

  for (int rq = 0; rq < RPB; ++rq) {
    const float4* th4 = (const float4*)(sTH + rq * 16);
    float4 t0 = th4[0], t1 = th4[1], t2 = th4[2], t3 = th4[3];
    float th[16] = {t0.x,t0.y,t0.z,t0.w, t1.x,t1.y,t1.z,t1.w,
                    t2.x,t2.y,t2.z,t2.w, t3.x,t3.y,t3.z,t3.w};
    float lx = bb.x, ly = bb.y, lz = bb.z, lw = bb.w;
    #pragma unroll
    for (int k = 0; k < 16; ++k) {
      lx += th[k] * w[k].x; ly += th[k] * w[k].y;
      lz += th[k] * w[k].z; lw += th[k] * w[k].w;
    }
    float s = __expf(lx) + __expf(ly) + __expf(lz) + __expf(lw);
    #pragma unroll
    for (int off = 32; off >= 1; off >>= 1) s += __shfl_xor(s, off);
    if (lane == 0) sPW[rq][wave] = s;
  }
  __syncthreads();
  if (tid < RPB) {
    float s = sPW[tid][0] + sPW[tid][1] + sPW[tid][2] + sPW[tid][3] + sPW[tid][4];
    pms[(long)(row0 + tid) * NCH + chunk] = s;
  }
}

// ---------------- Z = log(sum of partials) ----------------
__global__ __launch_bounds__(256) void k_reduce(const float* __restrict__ pms, float* __restrict__ Z) {
  int r = blockIdx.x * 256 + threadIdx.x;
  float s = 0.f;
  #pragma unroll
  for (int i = 0; i < NCH; ++i) s += pms[(long)r * NCH + i];
  Z[r] = logf(s);
}

// ---------------- pass 2: recompute logits, subtract Z, write ----------------
// grid (NCH, G2); whole 128x16 hcat tile + Z staged once, then sync-free streaming.
__global__ __launch_bounds__(NT) void k_wr(const float* __restrict__ hcat,
                                           const float* __restrict__ Wout,
                                           const float* __restrict__ bout,
                                           const float* __restrict__ Z,
                                           float* __restrict__ out) {
  const int RPB = TB / G2;                 // 128
  __shared__ float sTH[RPB * 16];          // 8 KB
  __shared__ float sZ[RPB];
  int tid = threadIdx.x;
  int chunk = blockIdx.x;
  int row0 = blockIdx.y * RPB;
  int col4 = chunk * (NT * 4) + tid * 4;

  float4 w[16];
  #pragma unroll
  for (int k = 0; k < 16; ++k) w[k] = *(const float4*)(Wout + k * V + col4);
  float4 bb = *(const float4*)(bout + col4);

  for (int i = tid; i < RPB * 16; i += NT) sTH[i] = hcat[row0 * 16 + i];
  for (int i = tid; i < RPB; i += NT) sZ[i] = Z[row0 + i];
  __syncthreads();

  for (int rq = 0; rq < RPB; ++rq) {
    const float4* th4 = (const float4*)(sTH + rq * 16);
    float4 t0 = th4[0], t1 = th4[1], t2 = th4[2], t3 = th4[3];
    float th[16] = {t0.x,t0.y,t0.z,t0.w, t1.x,t1.y,t1.z,t1.w,
                    t2.x,t2.y,t2.z,t2.w, t3.x,t3.y,t3.z,t3.w};
    float lx = bb.x, ly = bb.y, lz = bb.z, lw = bb.w;
    #pragma unroll
    for (int k = 0; k < 16; ++k) {
      lx += th[k] * w[k].x; ly += th[k] * w[k].y;
      lz += th[k] * w[k].z; lw += th[k] * w[k].w;
    }
    float Zq = sZ[rq];
    float4 o4;
    o4.x = lx - Zq; o4.y = ly - Zq; o4.z = lz - Zq; o4.w = lw - Zq;
    *(float4*)(out + (long)(row0 + rq) * V + col4) = o4;
  }
}

extern "C" void kernel_launch(void* const* d_in, const int* in_sizes, int n_in,
                              void* d_out, int out_size, void* d_ws, size_t ws_size,
                              hipStream_t stream) {
  (void)in_sizes; (void)n_in; (void)out_size; (void)ws_size;
  P1 p;
  p.x   = (const int*)  d_in[0];
  p.emb = (const float*)d_in[1];
  p.Wf1 = (const float*)d_in[2];  p.bf1 = (const float*)d_in[3];
  p.Wi1 = (const float*)d_in[4];  p.bi1 = (const float*)d_in[5];
  p.WC1 = (const float*)d_in[6];  p.bC1 = (const float*)d_in[7];
  p.Wo1 = (const float*)d_in[8];  p.bo1 = (const float*)d_in[9];
  p.Wf2 = (const float*)d_in[10]; p.bf2 = (const float*)d_in[11];
  p.Wi2 = (const float*)d_in[12]; p.bi2 = (const float*)d_in[13];
  p.WC2 = (const float*)d_in[14]; p.bC2 = (const float*)d_in[15];
  p.Wo2 = (const float*)d_in[16]; p.bo2 = (const float*)d_in[17];
  const float* Wout = (const float*)d_in[18];
  const float* bout = (const float*)d_in[19];

  float* pe   = (float*)d_ws;            // 2*11*TB = 180224 f
  float* hcat = pe + 2 * 11 * TB;        // TB*16   = 131072 f
  float* pms  = hcat + TB * 16;          // TB*NCH  = 204800 f
  float* Zr   = pms + TB * NCH;          // TB      =   8192 f
  float* out  = (float*)d_out;

  k_embed <<<dim3(TB / 256),  dim3(256), 0, stream>>>(p, pe);
  k_lstm  <<<dim3(2),         dim3(64),  0, stream>>>(p, pe, hcat);
  k_part  <<<dim3(NCH, G1),   dim3(NT),  0, stream>>>(hcat, Wout, bout, pms);
  k_reduce<<<dim3(TB / 256),  dim3(256), 0, stream>>>(pms, Zr);
  k_wr    <<<dim3(NCH, G2),   dim3(NT),  0, stream>>>(hcat, Wout, bout, Zr, out);
}

// Round 7
// 611.512 us; speedup vs baseline: 1.4525x; 1.2572x over previous
//
#include <hip/hip_runtime.h>
#include <hip/hip_bf16.h>
#include <math.h>

#define V 32000
#define T 128
#define B 64
#define E 32
#define H 8
#define TB (T*B)   // 8192

#define NT 320     // 5 waves; 4 cols/thread -> 1280 cols per chunk
#define NW 5
#define NCH 25     // 32000 / 1280 v-chunks
#define G1 32      // row-groups pass 1 (256 rows/block)
#define G2 64      // row-groups pass 2 (128 rows/block)

typedef float f32x2 __attribute__((ext_vector_type(2)));

// ---------------- params struct ----------------
struct P1 {
  const int* x; const float* emb;
  const float* Wf1; const float* bf1; const float* Wi1; const float* bi1;
  const float* WC1; const float* bC1; const float* Wo1; const float* bo1;
  const float* Wf2; const float* bf2; const float* Wi2; const float* bi2;
  const float* WC2; const float* bC2; const float* Wo2; const float* bo2;
};

__device__ __forceinline__ float sigm_f(float x) { return 1.f / (1.f + __expf(-x)); }
__device__ __forceinline__ float tanh_f(float x) { float e = __expf(2.f * x); return 1.f - 2.f / (e + 1.f); }

// ---------------- kernel 1: embed + e-part projections (bias folded in) ----------------
__global__ __launch_bounds__(256) void k_embed(P1 p, float* __restrict__ pe) {
  int r = blockIdx.x * 256 + threadIdx.x;
  int idx = p.x[r];
  const float* e = p.emb + (long)idx * E;
  float ev[E];
  #pragma unroll
  for (int k = 0; k < E; k += 4) {
    float4 v4 = *(const float4*)(e + k);
    ev[k] = v4.x; ev[k+1] = v4.y; ev[k+2] = v4.z; ev[k+3] = v4.w;
  }
  #pragma unroll
  for (int d = 0; d < 2; ++d) {
    const float* Wf = d ? p.Wf2 : p.Wf1;
    const float* Wi = d ? p.Wi2 : p.Wi1;
    const float* Wo = d ? p.Wo2 : p.Wo1;
    const float* WC = d ? p.WC2 : p.WC1;
    const float* bC = d ? p.bC2 : p.bC1;
    float af = (d ? p.bf2 : p.bf1)[0];
    float ai = (d ? p.bi2 : p.bi1)[0];
    float ao = (d ? p.bo2 : p.bo1)[0];
    float ac[H];
    #pragma unroll
    for (int j = 0; j < H; ++j) ac[j] = bC[j];
    #pragma unroll
    for (int k = 0; k < E; ++k) {
      float ek = ev[k];
      af += ek * Wf[8 + k];
      ai += ek * Wi[8 + k];
      ao += ek * Wo[8 + k];
      #pragma unroll
      for (int j = 0; j < H; ++j) ac[j] += ek * WC[(8 + k) * H + j];
    }
    float* ped = pe + d * 11 * TB;
    ped[0 * TB + r] = af;
    ped[1 * TB + r] = ai;
    ped[2 * TB + r] = ao;
    #pragma unroll
    for (int j = 0; j < H; ++j) ped[(3 + j) * TB + r] = ac[j];
  }
}

// ---------------- kernel 2: sequential LSTM (one block per direction) ----------------
__global__ __launch_bounds__(64) void k_lstm(P1 p, const float* __restrict__ pe, float* __restrict__ hcat) {
  int dir = blockIdx.x;
  int lane = threadIdx.x;
  const float* Wf = dir ? p.Wf2 : p.Wf1;
  const float* Wi = dir ? p.Wi2 : p.Wi1;
  const float* Wo = dir ? p.Wo2 : p.Wo1;
  const float* WC = dir ? p.WC2 : p.WC1;
  float wf[8], wi[8], wo[8], wc[8][8];
  #pragma unroll
  for (int k = 0; k < 8; ++k) { wf[k] = Wf[k]; wi[k] = Wi[k]; wo[k] = Wo[k]; }
  #pragma unroll
  for (int k = 0; k < 8; ++k)
    #pragma unroll
    for (int j = 0; j < 8; ++j) wc[k][j] = WC[k * H + j];

  float h[8], C[8];
  #pragma unroll
  for (int j = 0; j < 8; ++j) { h[j] = 0.f; C[j] = 0.f; }

  const float* ped = pe + dir * 11 * TB;

  int tf = dir ? (T - 1) : 0;
  int rf = tf * B + lane;
  float nf = ped[0 * TB + rf], ni = ped[1 * TB + rf], no_ = ped[2 * TB + rf];
  float nc[8];
  #pragma unroll
  for (int j = 0; j < 8; ++j) nc[j] = ped[(3 + j) * TB + rf];

  for (int s = 0; s < T; ++s) {
    int t = dir ? (T - 1 - s) : s;
    int r = t * B + lane;
    float af = nf, ai = ni, ao = no_;
    float ac[8];
    #pragma unroll
    for (int j = 0; j < 8; ++j) ac[j] = nc[j];

    if (s + 1 < T) {
      int t2 = dir ? (T - 2 - s) : (s + 1);
      int r2 = t2 * B + lane;
      nf = ped[0 * TB + r2]; ni = ped[1 * TB + r2]; no_ = ped[2 * TB + r2];
      #pragma unroll
      for (int j = 0; j < 8; ++j) nc[j] = ped[(3 + j) * TB + r2];
    }

    float* hc = hcat + r * 16 + dir * 8;
    #pragma unroll
    for (int j = 0; j < 8; ++j) hc[j] = h[j];

    #pragma unroll
    for (int k = 0; k < 8; ++k) {
      float hk = h[k];
      af += hk * wf[k];
      ai += hk * wi[k];
      ao += hk * wo[k];
      #pragma unroll
      for (int j = 0; j < 8; ++j) ac[j] += hk * wc[k][j];
    }
    float f = sigm_f(af), i = sigm_f(ai), o = sigm_f(ao);
    #pragma unroll
    for (int j = 0; j < 8; ++j) {
      float Cn = f * C[j] + i + tanh_f(ac[j]);
      C[j] = Cn;
      h[j] = o * tanh_f(Cn);
    }
  }
}

// ---------------- pass 1: partial sum-exp; Wout slice in registers ----------------
// grid (NCH, G1); block = cols [chunk*1280,+1280) x rows [rg*256,+256)
// One-time LDS stage; 16-row UNROLLED tiles (ILP); pk-fma via f32x2 accumulators.
__global__ __launch_bounds__(NT) void k_part(const float* __restrict__ hcat,
                                             const float* __restrict__ Wout,
                                             const float* __restrict__ bout,
                                             float* __restrict__ pms) {
  const int RPB = TB / G1;                 // 256 rows
  __shared__ float sTH[RPB * 16];          // 16 KB
  __shared__ float sPW[RPB][NW];           // 5 KB
  int tid = threadIdx.x;
  int wave = tid >> 6, lane = tid & 63;
  int chunk = blockIdx.x;
  int row0 = blockIdx.y * RPB;
  int col4 = chunk * (NT * 4) + tid * 4;

  for (int i = tid; i < RPB * 16; i += NT) sTH[i] = hcat[row0 * 16 + i];
  __syncthreads();

  f32x2 wlo[16], whi[16];
  #pragma unroll
  for (int k = 0; k < 16; ++k) {
    float4 w4 = *(const float4*)(Wout + k * V + col4);
    wlo[k].x = w4.x; wlo[k].y = w4.y;
    whi[k].x = w4.z; whi[k].y = w4.w;
  }
  float4 bb4 = *(const float4*)(bout + col4);

  for (int rt = 0; rt < RPB / 16; ++rt) {
    #pragma unroll
    for (int q = 0; q < 16; ++q) {
      int rq = rt * 16 + q;
      const float4* th4 = (const float4*)(sTH + rq * 16);
      float4 t0 = th4[0], t1 = th4[1], t2 = th4[2], t3 = th4[3];
      float th[16] = {t0.x,t0.y,t0.z,t0.w, t1.x,t1.y,t1.z,t1.w,
                      t2.x,t2.y,t2.z,t2.w, t3.x,t3.y,t3.z,t3.w};
      f32x2 axy; axy.x = bb4.x; axy.y = bb4.y;
      f32x2 azw; azw.x = bb4.z; azw.y = bb4.w;
      #pragma unroll
      for (int k = 0; k < 16; ++k) {
        axy += th[k] * wlo[k];               // v_pk_fma_f32
        azw += th[k] * whi[k];
      }
      float s = __expf(axy.x) + __expf(axy.y) + __expf(azw.x) + __expf(azw.y);
      #pragma unroll
      for (int off = 32; off >= 1; off >>= 1) s += __shfl_xor(s, off);
      if (lane == 0) sPW[rq][wave] = s;
    }
  }
  __syncthreads();
  if (tid < RPB) {
    float s = sPW[tid][0] + sPW[tid][1] + sPW[tid][2] + sPW[tid][3] + sPW[tid][4];
    pms[(long)(row0 + tid) * NCH + chunk] = s;
  }
}

// ---------------- Z = log(sum of partials) ----------------
__global__ __launch_bounds__(256) void k_reduce(const float* __restrict__ pms, float* __restrict__ Z) {
  int r = blockIdx.x * 256 + threadIdx.x;
  float s = 0.f;
  #pragma unroll
  for (int i = 0; i < NCH; ++i) s += pms[(long)r * NCH + i];
  Z[r] = logf(s);
}

// ---------------- pass 2: recompute logits, subtract Z, write ----------------
// grid (NCH, G2); one-time stage; 16-row UNROLLED tiles; pk-fma.
__global__ __launch_bounds__(NT) void k_wr(const float* __restrict__ hcat,
                                           const float* __restrict__ Wout,
                                           const float* __restrict__ bout,
                                           const float* __restrict__ Z,
                                           float* __restrict__ out) {
  const int RPB = TB / G2;                 // 128
  __shared__ float sTH[RPB * 16];          // 8 KB
  __shared__ float sZ[RPB];
  int tid = threadIdx.x;
  int chunk = blockIdx.x;
  int row0 = blockIdx.y * RPB;
  int col4 = chunk * (NT * 4) + tid * 4;

  f32x2 wlo[16], whi[16];
  #pragma unroll
  for (int k = 0; k < 16; ++k) {
    float4 w4 = *(const float4*)(Wout + k * V + col4);
    wlo[k].x = w4.x; wlo[k].y = w4.y;
    whi[k].x = w4.z; whi[k].y = w4.w;
  }
  float4 bb4 = *(const float4*)(bout + col4);

  for (int i = tid; i < RPB * 16; i += NT) sTH[i] = hcat[row0 * 16 + i];
  for (int i = tid; i < RPB; i += NT) sZ[i] = Z[row0 + i];
  __syncthreads();

  for (int rt = 0; rt < RPB / 16; ++rt) {
    #pragma unroll
    for (int q = 0; q < 16; ++q) {
      int rq = rt * 16 + q;
      const float4* th4 = (const float4*)(sTH + rq * 16);
      float4 t0 = th4[0], t1 = th4[1], t2 = th4[2], t3 = th4[3];
      float th[16] = {t0.x,t0.y,t0.z,t0.w, t1.x,t1.y,t1.z,t1.w,
                      t2.x,t2.y,t2.z,t2.w, t3.x,t3.y,t3.z,t3.w};
      f32x2 axy; axy.x = bb4.x; axy.y = bb4.y;
      f32x2 azw; azw.x = bb4.z; azw.y = bb4.w;
      #pragma unroll
      for (int k = 0; k < 16; ++k) {
        axy += th[k] * wlo[k];               // v_pk_fma_f32
        azw += th[k] * whi[k];
      }
      float Zq = sZ[rq];
      float4 o4;
      o4.x = axy.x - Zq; o4.y = axy.y - Zq; o4.z = azw.x - Zq; o4.w = azw.y - Zq;
      *(float4*)(out + (long)(row0 + rq) * V + col4) = o4;
    }
  }
}

extern "C" void kernel_launch(void* const* d_in, const int* in_sizes, int n_in,
                              void* d_out, int out_size, void* d_ws, size_t ws_size,
                              hipStream_t stream) {
  (void)in_sizes; (void)n_in; (void)out_size; (void)ws_size;
  P1 p;
  p.x   = (const int*)  d_in[0];
  p.emb = (const float*)d_in[1];
  p.Wf1 = (const float*)d_in[2];  p.bf1 = (const float*)d_in[3];
  p.Wi1 = (const float*)d_in[4];  p.bi1 = (const float*)d_in[5];
  p.WC1 = (const float*)d_in[6];  p.bC1 = (const float*)d_in[7];
  p.Wo1 = (const float*)d_in[8];  p.bo1 = (const float*)d_in[9];
  p.Wf2 = (const float*)d_in[10]; p.bf2 = (const float*)d_in[11];
  p.Wi2 = (const float*)d_in[12]; p.bi2 = (const float*)d_in[13];
  p.WC2 = (const float*)d_in[14]; p.bC2 = (const float*)d_in[15];
  p.Wo2 = (const float*)d_in[16]; p.bo2 = (const float*)d_in[17];
  const float* Wout = (const float*)d_in[18];
  const float* bout = (const float*)d_in[19];

  float* pe   = (float*)d_ws;            // 2*11*TB = 180224 f
  float* hcat = pe + 2 * 11 * TB;        // TB*16   = 131072 f
  float* pms  = hcat + TB * 16;          // TB*NCH  = 204800 f
  float* Zr   = pms + TB * NCH;          // TB      =   8192 f
  float* out  = (float*)d_out;

  k_embed <<<dim3(TB / 256),  dim3(256), 0, stream>>>(p, pe);
  k_lstm  <<<dim3(2),         dim3(64),  0, stream>>>(p, pe, hcat);
  k_part  <<<dim3(NCH, G1),   dim3(NT),  0, stream>>>(hcat, Wout, bout, pms);
  k_reduce<<<dim3(TB / 256),  dim3(256), 0, stream>>>(pms, Zr);
  k_wr    <<<dim3(NCH, G2),   dim3(NT),  0, stream>>>(hcat, Wout, bout, Zr, out);
}

// Round 8
// 600.580 us; speedup vs baseline: 1.4789x; 1.0182x over previous
//
#include <hip/hip_runtime.h>
#include <hip/hip_bf16.h>
#include <math.h>

#define V 32000
#define T 128
#define B 64
#define E 32
#define H 8
#define TB (T*B)   // 8192

#define NT 320     // 5 waves
#define NW 5
#define NCH 25     // pass-1 v-chunks (1280 cols, 4 cols/thread)
#define NCH2 50    // pass-2 v-chunks (640 cols, 2 cols/thread)
#define G1 32      // row-groups pass 1 (256 rows/block)
#define G2 64      // row-groups pass 2 (128 rows/block)

typedef float f32x2 __attribute__((ext_vector_type(2)));

// ---------------- params struct ----------------
struct P1 {
  const int* x; const float* emb;
  const float* Wf1; const float* bf1; const float* Wi1; const float* bi1;
  const float* WC1; const float* bC1; const float* Wo1; const float* bo1;
  const float* Wf2; const float* bf2; const float* Wi2; const float* bi2;
  const float* WC2; const float* bC2; const float* Wo2; const float* bo2;
};

__device__ __forceinline__ float sigm_f(float x) { return 1.f / (1.f + __expf(-x)); }
__device__ __forceinline__ float tanh_f(float x) { float e = __expf(2.f * x); return 1.f - 2.f / (e + 1.f); }

// ---------------- kernel 1: embed + e-part projections (bias folded in) ----------------
__global__ __launch_bounds__(256) void k_embed(P1 p, float* __restrict__ pe) {
  int r = blockIdx.x * 256 + threadIdx.x;
  int idx = p.x[r];
  const float* e = p.emb + (long)idx * E;
  float ev[E];
  #pragma unroll
  for (int k = 0; k < E; k += 4) {
    float4 v4 = *(const float4*)(e + k);
    ev[k] = v4.x; ev[k+1] = v4.y; ev[k+2] = v4.z; ev[k+3] = v4.w;
  }
  #pragma unroll
  for (int d = 0; d < 2; ++d) {
    const float* Wf = d ? p.Wf2 : p.Wf1;
    const float* Wi = d ? p.Wi2 : p.Wi1;
    const float* Wo = d ? p.Wo2 : p.Wo1;
    const float* WC = d ? p.WC2 : p.WC1;
    const float* bC = d ? p.bC2 : p.bC1;
    float af = (d ? p.bf2 : p.bf1)[0];
    float ai = (d ? p.bi2 : p.bi1)[0];
    float ao = (d ? p.bo2 : p.bo1)[0];
    float ac[H];
    #pragma unroll
    for (int j = 0; j < H; ++j) ac[j] = bC[j];
    #pragma unroll
    for (int k = 0; k < E; ++k) {
      float ek = ev[k];
      af += ek * Wf[8 + k];
      ai += ek * Wi[8 + k];
      ao += ek * Wo[8 + k];
      #pragma unroll
      for (int j = 0; j < H; ++j) ac[j] += ek * WC[(8 + k) * H + j];
    }
    float* ped = pe + d * 11 * TB;
    ped[0 * TB + r] = af;
    ped[1 * TB + r] = ai;
    ped[2 * TB + r] = ao;
    #pragma unroll
    for (int j = 0; j < H; ++j) ped[(3 + j) * TB + r] = ac[j];
  }
}

// ---------------- kernel 2: sequential LSTM (one block per direction) ----------------
__global__ __launch_bounds__(64) void k_lstm(P1 p, const float* __restrict__ pe, float* __restrict__ hcat) {
  int dir = blockIdx.x;
  int lane = threadIdx.x;
  const float* Wf = dir ? p.Wf2 : p.Wf1;
  const float* Wi = dir ? p.Wi2 : p.Wi1;
  const float* Wo = dir ? p.Wo2 : p.Wo1;
  const float* WC = dir ? p.WC2 : p.WC1;
  float wf[8], wi[8], wo[8], wc[8][8];
  #pragma unroll
  for (int k = 0; k < 8; ++k) { wf[k] = Wf[k]; wi[k] = Wi[k]; wo[k] = Wo[k]; }
  #pragma unroll
  for (int k = 0; k < 8; ++k)
    #pragma unroll
    for (int j = 0; j < 8; ++j) wc[k][j] = WC[k * H + j];

  float h[8], C[8];
  #pragma unroll
  for (int j = 0; j < 8; ++j) { h[j] = 0.f; C[j] = 0.f; }

  const float* ped = pe + dir * 11 * TB;

  int tf = dir ? (T - 1) : 0;
  int rf = tf * B + lane;
  float nf = ped[0 * TB + rf], ni = ped[1 * TB + rf], no_ = ped[2 * TB + rf];
  float nc[8];
  #pragma unroll
  for (int j = 0; j < 8; ++j) nc[j] = ped[(3 + j) * TB + rf];

  for (int s = 0; s < T; ++s) {
    int t = dir ? (T - 1 - s) : s;
    int r = t * B + lane;
    float af = nf, ai = ni, ao = no_;
    float ac[8];
    #pragma unroll
    for (int j = 0; j < 8; ++j) ac[j] = nc[j];

    if (s + 1 < T) {
      int t2 = dir ? (T - 2 - s) : (s + 1);
      int r2 = t2 * B + lane;
      nf = ped[0 * TB + r2]; ni = ped[1 * TB + r2]; no_ = ped[2 * TB + r2];
      #pragma unroll
      for (int j = 0; j < 8; ++j) nc[j] = ped[(3 + j) * TB + r2];
    }

    float* hc = hcat + r * 16 + dir * 8;
    #pragma unroll
    for (int j = 0; j < 8; ++j) hc[j] = h[j];

    #pragma unroll
    for (int k = 0; k < 8; ++k) {
      float hk = h[k];
      af += hk * wf[k];
      ai += hk * wi[k];
      ao += hk * wo[k];
      #pragma unroll
      for (int j = 0; j < 8; ++j) ac[j] += hk * wc[k][j];
    }
    float f = sigm_f(af), i = sigm_f(ai), o = sigm_f(ao);
    #pragma unroll
    for (int j = 0; j < 8; ++j) {
      float Cn = f * C[j] + i + tanh_f(ac[j]);
      C[j] = Cn;
      h[j] = o * tanh_f(Cn);
    }
  }
}

// ---------------- pass 1: partial sum-exp; Wout slice in registers (R7 form) -------
__global__ __launch_bounds__(NT) void k_part(const float* __restrict__ hcat,
                                             const float* __restrict__ Wout,
                                             const float* __restrict__ bout,
                                             float* __restrict__ pms) {
  const int RPB = TB / G1;                 // 256 rows
  __shared__ float sTH[RPB * 16];          // 16 KB
  __shared__ float sPW[RPB][NW];           // 5 KB
  int tid = threadIdx.x;
  int wave = tid >> 6, lane = tid & 63;
  int chunk = blockIdx.x;
  int row0 = blockIdx.y * RPB;
  int col4 = chunk * (NT * 4) + tid * 4;

  for (int i = tid; i < RPB * 16; i += NT) sTH[i] = hcat[row0 * 16 + i];
  __syncthreads();

  f32x2 wlo[16], whi[16];
  #pragma unroll
  for (int k = 0; k < 16; ++k) {
    float4 w4 = *(const float4*)(Wout + k * V + col4);
    wlo[k].x = w4.x; wlo[k].y = w4.y;
    whi[k].x = w4.z; whi[k].y = w4.w;
  }
  float4 bb4 = *(const float4*)(bout + col4);

  for (int rt = 0; rt < RPB / 16; ++rt) {
    #pragma unroll
    for (int q = 0; q < 16; ++q) {
      int rq = rt * 16 + q;
      const float4* th4 = (const float4*)(sTH + rq * 16);
      float4 t0 = th4[0], t1 = th4[1], t2 = th4[2], t3 = th4[3];
      float th[16] = {t0.x,t0.y,t0.z,t0.w, t1.x,t1.y,t1.z,t1.w,
                      t2.x,t2.y,t2.z,t2.w, t3.x,t3.y,t3.z,t3.w};
      f32x2 axy; axy.x = bb4.x; axy.y = bb4.y;
      f32x2 azw; azw.x = bb4.z; azw.y = bb4.w;
      #pragma unroll
      for (int k = 0; k < 16; ++k) {
        axy += th[k] * wlo[k];               // v_pk_fma_f32
        azw += th[k] * whi[k];
      }
      float s = __expf(axy.x) + __expf(axy.y) + __expf(azw.x) + __expf(azw.y);
      #pragma unroll
      for (int off = 32; off >= 1; off >>= 1) s += __shfl_xor(s, off);
      if (lane == 0) sPW[rq][wave] = s;
    }
  }
  __syncthreads();
  if (tid < RPB) {
    float s = sPW[tid][0] + sPW[tid][1] + sPW[tid][2] + sPW[tid][3] + sPW[tid][4];
    pms[(long)(row0 + tid) * NCH + chunk] = s;
  }
}

// ---------------- Z = log(sum of partials) ----------------
__global__ __launch_bounds__(256) void k_reduce(const float* __restrict__ pms, float* __restrict__ Z) {
  int r = blockIdx.x * 256 + threadIdx.x;
  float s = 0.f;
  #pragma unroll
  for (int i = 0; i < NCH; ++i) s += pms[(long)r * NCH + i];
  Z[r] = logf(s);
}

// ---------------- pass 2: slim high-occupancy writer ----------------
// grid (NCH2, G2); 2 cols/thread (W = 32 VGPR), launch_bounds(320,6) -> <=85 VGPR,
// 24 waves/CU target. 8-row unrolled tiles for ILP at lower register pressure.
__global__ __launch_bounds__(NT, 6) void k_wr(const float* __restrict__ hcat,
                                              const float* __restrict__ Wout,
                                              const float* __restrict__ bout,
                                              const float* __restrict__ Z,
                                              float* __restrict__ out) {
  const int RPB = TB / G2;                 // 128
  __shared__ float sTH[RPB * 16];          // 8 KB
  __shared__ float sZ[RPB];
  int tid = threadIdx.x;
  int chunk = blockIdx.x;                  // 0..49
  int row0 = blockIdx.y * RPB;
  int col2 = chunk * (NT * 2) + tid * 2;

  f32x2 w[16];
  #pragma unroll
  for (int k = 0; k < 16; ++k) w[k] = *(const f32x2*)(Wout + k * V + col2);
  f32x2 bb = *(const f32x2*)(bout + col2);

  for (int i = tid; i < RPB * 16; i += NT) sTH[i] = hcat[row0 * 16 + i];
  for (int i = tid; i < RPB; i += NT) sZ[i] = Z[row0 + i];
  __syncthreads();

  for (int rt = 0; rt < RPB / 8; ++rt) {
    #pragma unroll
    for (int q = 0; q < 8; ++q) {
      int rq = rt * 8 + q;
      const float4* th4 = (const float4*)(sTH + rq * 16);
      float4 t0 = th4[0], t1 = th4[1], t2 = th4[2], t3 = th4[3];
      float th[16] = {t0.x,t0.y,t0.z,t0.w, t1.x,t1.y,t1.z,t1.w,
                      t2.x,t2.y,t2.z,t2.w, t3.x,t3.y,t3.z,t3.w};
      f32x2 a; a.x = bb.x; a.y = bb.y;
      #pragma unroll
      for (int k = 0; k < 16; ++k) a += th[k] * w[k];   // v_pk_fma_f32
      float Zq = sZ[rq];
      float2 o2;
      o2.x = a.x - Zq; o2.y = a.y - Zq;
      *(float2*)(out + (long)(row0 + rq) * V + col2) = o2;
    }
  }
}

extern "C" void kernel_launch(void* const* d_in, const int* in_sizes, int n_in,
                              void* d_out, int out_size, void* d_ws, size_t ws_size,
                              hipStream_t stream) {
  (void)in_sizes; (void)n_in; (void)out_size; (void)ws_size;
  P1 p;
  p.x   = (const int*)  d_in[0];
  p.emb = (const float*)d_in[1];
  p.Wf1 = (const float*)d_in[2];  p.bf1 = (const float*)d_in[3];
  p.Wi1 = (const float*)d_in[4];  p.bi1 = (const float*)d_in[5];
  p.WC1 = (const float*)d_in[6];  p.bC1 = (const float*)d_in[7];
  p.Wo1 = (const float*)d_in[8];  p.bo1 = (const float*)d_in[9];
  p.Wf2 = (const float*)d_in[10]; p.bf2 = (const float*)d_in[11];
  p.Wi2 = (const float*)d_in[12]; p.bi2 = (const float*)d_in[13];
  p.WC2 = (const float*)d_in[14]; p.bC2 = (const float*)d_in[15];
  p.Wo2 = (const float*)d_in[16]; p.bo2 = (const float*)d_in[17];
  const float* Wout = (const float*)d_in[18];
  const float* bout = (const float*)d_in[19];

  float* pe   = (float*)d_ws;            // 2*11*TB = 180224 f
  float* hcat = pe + 2 * 11 * TB;        // TB*16   = 131072 f
  float* pms  = hcat + TB * 16;          // TB*NCH  = 204800 f
  float* Zr   = pms + TB * NCH;          // TB      =   8192 f
  float* out  = (float*)d_out;

  k_embed <<<dim3(TB / 256),  dim3(256), 0, stream>>>(p, pe);
  k_lstm  <<<dim3(2),         dim3(64),  0, stream>>>(p, pe, hcat);
  k_part  <<<dim3(NCH, G1),   dim3(NT),  0, stream>>>(hcat, Wout, bout, pms);
  k_reduce<<<dim3(TB / 256),  dim3(256), 0, stream>>>(pms, Zr);
  k_wr    <<<dim3(NCH2, G2),  dim3(NT),  0, stream>>>(hcat, Wout, bout, Zr, out);
}

// Round 9
// 547.741 us; speedup vs baseline: 1.6216x; 1.0965x over previous
//
#include <hip/hip_runtime.h>
#include <hip/hip_bf16.h>
#include <math.h>

#define V 32000
#define T 128
#define B 64
#define E 32
#define H 8
#define TB (T*B)   // 8192

#define CS 10      // col-groups for MFMA kernels; 40 wave-slices of 800 cols
#define TPW 50     // 16-col tiles per wave-slice (10*4*50*16 = 32000)
#define NSL 40     // total slices

typedef short bf16x8 __attribute__((ext_vector_type(8)));
typedef float f32x4  __attribute__((ext_vector_type(4)));

// ---------------- params struct ----------------
struct P1 {
  const int* x; const float* emb;
  const float* Wf1; const float* bf1; const float* Wi1; const float* bi1;
  const float* WC1; const float* bC1; const float* Wo1; const float* bo1;
  const float* Wf2; const float* bf2; const float* Wi2; const float* bi2;
  const float* WC2; const float* bC2; const float* Wo2; const float* bo2;
};

__device__ __forceinline__ float sigm_f(float x) { return 1.f / (1.f + __expf(-x)); }
__device__ __forceinline__ float tanh_f(float x) { float e = __expf(2.f * x); return 1.f - 2.f / (e + 1.f); }
__device__ __forceinline__ ushort f2bf(float f) {            // RNE fp32->bf16
  unsigned u = __float_as_uint(f);
  u = (u + 0x7FFFu + ((u >> 16) & 1u)) >> 16;
  return (ushort)u;
}

// ---------------- kernel 1: embed + e-part projections (bias folded in) ----------------
__global__ __launch_bounds__(256) void k_embed(P1 p, float* __restrict__ pe) {
  int r = blockIdx.x * 256 + threadIdx.x;
  int idx = p.x[r];
  const float* e = p.emb + (long)idx * E;
  float ev[E];
  #pragma unroll
  for (int k = 0; k < E; k += 4) {
    float4 v4 = *(const float4*)(e + k);
    ev[k] = v4.x; ev[k+1] = v4.y; ev[k+2] = v4.z; ev[k+3] = v4.w;
  }
  #pragma unroll
  for (int d = 0; d < 2; ++d) {
    const float* Wf = d ? p.Wf2 : p.Wf1;
    const float* Wi = d ? p.Wi2 : p.Wi1;
    const float* Wo = d ? p.Wo2 : p.Wo1;
    const float* WC = d ? p.WC2 : p.WC1;
    const float* bC = d ? p.bC2 : p.bC1;
    float af = (d ? p.bf2 : p.bf1)[0];
    float ai = (d ? p.bi2 : p.bi1)[0];
    float ao = (d ? p.bo2 : p.bo1)[0];
    float ac[H];
    #pragma unroll
    for (int j = 0; j < H; ++j) ac[j] = bC[j];
    #pragma unroll
    for (int k = 0; k < E; ++k) {
      float ek = ev[k];
      af += ek * Wf[8 + k];
      ai += ek * Wi[8 + k];
      ao += ek * Wo[8 + k];
      #pragma unroll
      for (int j = 0; j < H; ++j) ac[j] += ek * WC[(8 + k) * H + j];
    }
    float* ped = pe + d * 11 * TB;
    ped[0 * TB + r] = af;
    ped[1 * TB + r] = ai;
    ped[2 * TB + r] = ao;
    #pragma unroll
    for (int j = 0; j < H; ++j) ped[(3 + j) * TB + r] = ac[j];
  }
}

// ---------------- kernel 2: sequential LSTM (one block per direction) ----------------
__global__ __launch_bounds__(64) void k_lstm(P1 p, const float* __restrict__ pe, float* __restrict__ hcat) {
  int dir = blockIdx.x;
  int lane = threadIdx.x;
  const float* Wf = dir ? p.Wf2 : p.Wf1;
  const float* Wi = dir ? p.Wi2 : p.Wi1;
  const float* Wo = dir ? p.Wo2 : p.Wo1;
  const float* WC = dir ? p.WC2 : p.WC1;
  float wf[8], wi[8], wo[8], wc[8][8];
  #pragma unroll
  for (int k = 0; k < 8; ++k) { wf[k] = Wf[k]; wi[k] = Wi[k]; wo[k] = Wo[k]; }
  #pragma unroll
  for (int k = 0; k < 8; ++k)
    #pragma unroll
    for (int j = 0; j < 8; ++j) wc[k][j] = WC[k * H + j];

  float h[8], C[8];
  #pragma unroll
  for (int j = 0; j < 8; ++j) { h[j] = 0.f; C[j] = 0.f; }

  const float* ped = pe + dir * 11 * TB;

  int tf = dir ? (T - 1) : 0;
  int rf = tf * B + lane;
  float nf = ped[0 * TB + rf], ni = ped[1 * TB + rf], no_ = ped[2 * TB + rf];
  float nc[8];
  #pragma unroll
  for (int j = 0; j < 8; ++j) nc[j] = ped[(3 + j) * TB + rf];

  for (int s = 0; s < T; ++s) {
    int t = dir ? (T - 1 - s) : s;
    int r = t * B + lane;
    float af = nf, ai = ni, ao = no_;
    float ac[8];
    #pragma unroll
    for (int j = 0; j < 8; ++j) ac[j] = nc[j];

    if (s + 1 < T) {
      int t2 = dir ? (T - 2 - s) : (s + 1);
      int r2 = t2 * B + lane;
      nf = ped[0 * TB + r2]; ni = ped[1 * TB + r2]; no_ = ped[2 * TB + r2];
      #pragma unroll
      for (int j = 0; j < 8; ++j) nc[j] = ped[(3 + j) * TB + r2];
    }

    float* hc = hcat + r * 16 + dir * 8;
    #pragma unroll
    for (int j = 0; j < 8; ++j) hc[j] = h[j];

    #pragma unroll
    for (int k = 0; k < 8; ++k) {
      float hk = h[k];
      af += hk * wf[k];
      ai += hk * wi[k];
      ao += hk * wo[k];
      #pragma unroll
      for (int j = 0; j < 8; ++j) ac[j] += hk * wc[k][j];
    }
    float f = sigm_f(af), i = sigm_f(ai), o = sigm_f(ao);
    #pragma unroll
    for (int j = 0; j < 8; ++j) {
      float Cn = f * C[j] + i + tanh_f(ac[j]);
      C[j] = Cn;
      h[j] = o * tanh_f(Cn);
    }
  }
}

// ---------------- prep: Wout fp32 [16][V] -> Wbf bf16 [V][32] (K padded) ------------
__global__ __launch_bounds__(256) void k_cvtW(const float* __restrict__ Wout,
                                              ushort* __restrict__ Wbf) {
  int c = blockIdx.x * 256 + threadIdx.x;
  ushort tmp[32];
  #pragma unroll
  for (int k = 0; k < 16; ++k) tmp[k] = f2bf(Wout[k * V + c]);
  #pragma unroll
  for (int k = 16; k < 32; ++k) tmp[k] = 0;
  #pragma unroll
  for (int i = 0; i < 4; ++i)
    *(bf16x8*)(Wbf + c * 32 + i * 8) = *(bf16x8*)(tmp + i * 8);
}

// ---------------- prep: hcat fp32 [TB][16] -> thbf bf16 [TB][32] (K padded) ---------
__global__ __launch_bounds__(256) void k_cvtH(const float* __restrict__ hcat,
                                              ushort* __restrict__ thbf) {
  int r = blockIdx.x * 256 + threadIdx.x;
  ushort tmp[32];
  #pragma unroll
  for (int k = 0; k < 16; ++k) tmp[k] = f2bf(hcat[r * 16 + k]);
  #pragma unroll
  for (int k = 16; k < 32; ++k) tmp[k] = 0;
  #pragma unroll
  for (int i = 0; i < 4; ++i)
    *(bf16x8*)(thbf + r * 32 + i * 8) = *(bf16x8*)(tmp + i * 8);
}

// ---------------- pass 1 (MFMA): per-slice sum of exp(logit) -> pms[row][NSL] -------
// grid (CS, TB/16); block 256 = 4 waves; wave = 16 rows x 800 cols.
__global__ __launch_bounds__(256) void k_sum(const ushort* __restrict__ thbf,
                                             const ushort* __restrict__ Wbf,
                                             const float* __restrict__ bout,
                                             float* __restrict__ pms) {
  int tid = threadIdx.x;
  int wv = tid >> 6, l = tid & 63;
  int r0 = blockIdx.y * 16;
  int slice = blockIdx.x * 4 + wv;
  int cbase = slice * (TPW * 16);

  bf16x8 A = *(const bf16x8*)(thbf + (r0 + (l & 15)) * 32 + (l >> 4) * 8);

  float racc[4] = {0.f, 0.f, 0.f, 0.f};
  for (int t = 0; t < TPW; ++t) {
    int c = cbase + t * 16 + (l & 15);
    bf16x8 Bf = *(const bf16x8*)(Wbf + c * 32 + (l >> 4) * 8);
    float bb = bout[c];
    f32x4 acc = {0.f, 0.f, 0.f, 0.f};
    acc = __builtin_amdgcn_mfma_f32_16x16x32_bf16(A, Bf, acc, 0, 0, 0);
    racc[0] += __expf(acc[0] + bb);
    racc[1] += __expf(acc[1] + bb);
    racc[2] += __expf(acc[2] + bb);
    racc[3] += __expf(acc[3] + bb);
  }
  #pragma unroll
  for (int j = 0; j < 4; ++j) {
    float s = racc[j];
    s += __shfl_xor(s, 1); s += __shfl_xor(s, 2);
    s += __shfl_xor(s, 4); s += __shfl_xor(s, 8);
    if ((l & 15) == 0)
      pms[(long)(r0 + (l >> 4) * 4 + j) * NSL + slice] = s;
  }
}

// ---------------- Z = log(sum of partials) ----------------
__global__ __launch_bounds__(256) void k_reduce(const float* __restrict__ pms, float* __restrict__ Z) {
  int r = blockIdx.x * 256 + threadIdx.x;
  float s = 0.f;
  #pragma unroll
  for (int i = 0; i < NSL; ++i) s += pms[(long)r * NSL + i];
  Z[r] = logf(s);
}

// ---------------- pass 2 (MFMA): logits - Z -> out ----------------
// grid (CS, TB/16); block 256 = 4 waves; wave = 16 rows x 800 cols.
__global__ __launch_bounds__(256) void k_wr(const ushort* __restrict__ thbf,
                                            const ushort* __restrict__ Wbf,
                                            const float* __restrict__ bout,
                                            const float* __restrict__ Z,
                                            float* __restrict__ out) {
  int tid = threadIdx.x;
  int wv = tid >> 6, l = tid & 63;
  int r0 = blockIdx.y * 16;
  int slice = blockIdx.x * 4 + wv;
  int cbase = slice * (TPW * 16);

  bf16x8 A = *(const bf16x8*)(thbf + (r0 + (l & 15)) * 32 + (l >> 4) * 8);
  float Z4[4];
  #pragma unroll
  for (int j = 0; j < 4; ++j) Z4[j] = Z[r0 + (l >> 4) * 4 + j];

  for (int t = 0; t < TPW; ++t) {
    int c = cbase + t * 16 + (l & 15);
    bf16x8 Bf = *(const bf16x8*)(Wbf + c * 32 + (l >> 4) * 8);
    float bb = bout[c];
    f32x4 acc = {0.f, 0.f, 0.f, 0.f};
    acc = __builtin_amdgcn_mfma_f32_16x16x32_bf16(A, Bf, acc, 0, 0, 0);
    #pragma unroll
    for (int j = 0; j < 4; ++j)
      out[(long)(r0 + (l >> 4) * 4 + j) * V + c] = acc[j] + bb - Z4[j];
  }
}

extern "C" void kernel_launch(void* const* d_in, const int* in_sizes, int n_in,
                              void* d_out, int out_size, void* d_ws, size_t ws_size,
                              hipStream_t stream) {
  (void)in_sizes; (void)n_in; (void)out_size; (void)ws_size;
  P1 p;
  p.x   = (const int*)  d_in[0];
  p.emb = (const float*)d_in[1];
  p.Wf1 = (const float*)d_in[2];  p.bf1 = (const float*)d_in[3];
  p.Wi1 = (const float*)d_in[4];  p.bi1 = (const float*)d_in[5];
  p.WC1 = (const float*)d_in[6];  p.bC1 = (const float*)d_in[7];
  p.Wo1 = (const float*)d_in[8];  p.bo1 = (const float*)d_in[9];
  p.Wf2 = (const float*)d_in[10]; p.bf2 = (const float*)d_in[11];
  p.Wi2 = (const float*)d_in[12]; p.bi2 = (const float*)d_in[13];
  p.WC2 = (const float*)d_in[14]; p.bC2 = (const float*)d_in[15];
  p.Wo2 = (const float*)d_in[16]; p.bo2 = (const float*)d_in[17];
  const float* Wout = (const float*)d_in[18];
  const float* bout = (const float*)d_in[19];

  float*  pe   = (float*)d_ws;             // 180224 f
  float*  hcat = pe + 2 * 11 * TB;         // 131072 f
  float*  Zr   = hcat + TB * 16;           //   8192 f
  float*  pms  = Zr + TB;                  // 327680 f (TB*NSL)
  ushort* thbf = (ushort*)(pms + (long)TB * NSL);   // TB*32 ushort (16B-aligned)
  ushort* Wbf  = thbf + (long)TB * 32;              // V*32 ushort
  float*  out  = (float*)d_out;            // total ws ~ 5.2 MB

  k_embed <<<dim3(TB / 256),   dim3(256), 0, stream>>>(p, pe);
  k_lstm  <<<dim3(2),          dim3(64),  0, stream>>>(p, pe, hcat);
  k_cvtW  <<<dim3(V / 256),    dim3(256), 0, stream>>>(Wout, Wbf);
  k_cvtH  <<<dim3(TB / 256),   dim3(256), 0, stream>>>(hcat, thbf);
  k_sum   <<<dim3(CS, TB/16),  dim3(256), 0, stream>>>(thbf, Wbf, bout, pms);
  k_reduce<<<dim3(TB / 256),   dim3(256), 0, stream>>>(pms, Zr);
  k_wr    <<<dim3(CS, TB/16),  dim3(256), 0, stream>>>(thbf, Wbf, bout, Zr, out);
}